// Round 14
// baseline (170.841 us; speedup 1.0000x reference)
//
#include <hip/hip_runtime.h>

#define TT 140
#define BB 8192
#define HH 64
#define BT 16   // batch tile per block (MFMA N)
#define WIN 4   // steps per barrier window (TT = 35 * WIN exactly)
#define K_TANH 2.88539008178f

typedef _Float16 half4 __attribute__((ext_vector_type(4)));
typedef float    f32x4 __attribute__((ext_vector_type(4)));

// K=16 f16 MFMA: D/B layout identity (D: col=lane&15,row=4q+r ; B: col=lane&15,
// k=4q+i) lets tanh(D_g) feed the next MFMA's B k-frag kk=g DIRECTLY.
#define MFMA16(a,b,c) __builtin_amdgcn_mfma_f32_16x16x16f16(a, b, c, 0, 0, 0)

// tanh from PRE-SCALED argument (K_TANH folded into weights/biases)
__device__ __forceinline__ float tanh_ps(float as) {
    float e = __builtin_amdgcn_exp2f(as);
    return 1.0f - 2.0f * __builtin_amdgcn_rcpf(e + 1.0f);
}

__device__ __forceinline__ half4 ldw4(const float* p, float s) {
    f32x4 w = *(const f32x4*)p;
    half4 h;
    #pragma unroll
    for (int i = 0; i < 4; ++i) h[i] = (_Float16)(s * w[i]);
    return h;
}

// WAVE-SPECIALIZED + WINDOWED pipeline. r12 (2-wave specialized, reg-resident
// h, barrier/step) = 103us with ~1100 cyc/step stall: the per-step
// __syncthreads() drains vmcnt(0) (wave B's global y-store, 300-900 cyc) and
// pays 141x two-wave arrival skew on latency-dominated chains. This version:
//  - barrier every WIN=4 steps (A's h0 recurrence is register-self-contained;
//    B lags a FULL window; ei ring of 2*WIN=8 buffers keeps writer/reader
//    windows disjoint mod 8)  -> 36 barriers instead of 141
//  - y goes to LDS pps, flushed in epilogue -> no vmcnt in the loop at all
// Within A's unrolled window the compiler software-pipelines step p+1's L0
// MFMAs against step p's ih1 MFMAs (independent given H0(p)).
__global__ __launch_bounds__(128, 1)
void rnn_kernel(const float* __restrict__ x,
                const float* __restrict__ h_state,
                const float* __restrict__ W_ih0,
                const float* __restrict__ W_hh0,
                const float* __restrict__ b_ih0,
                const float* __restrict__ b_hh0,
                const float* __restrict__ W_ih1,
                const float* __restrict__ W_hh1,
                const float* __restrict__ b_ih1,
                const float* __restrict__ b_hh1,
                const float* __restrict__ W_out,
                const float* __restrict__ b_out,
                float* __restrict__ out)
{
    __shared__ float xs[TT * 17];          // x staged [t][b]          (9.5 KB)
    __shared__ float pps[TT * 17];         // y staged [t][b]          (9.5 KB)
    __shared__ f32x4 ei[2 * WIN][4][64];   // ih1 partials ring        (32 KB)

    const int tid  = threadIdx.x;
    const int wid  = tid >> 6;        // 0 = wave A (L0+ih1), 1 = wave B (L1+proj)
    const int lane = tid & 63;
    const int n    = lane & 15;       // MFMA col: batch within tile
    const int q    = lane >> 4;       // quad
    const int b0   = blockIdx.x * BT;

    // ---- per-role constants ----
    half4 A0[4][4], AI[4][4], AH[4][4];
    float e00[4][4], e10[4][4], e01[4][4], WO[4][4];
    half4 H0[4], H1[4];
    float bout = 0.f;
    if (wid == 0) {
        #pragma unroll
        for (int g = 0; g < 4; ++g)
        #pragma unroll
        for (int kk = 0; kk < 4; ++kk) {
            const int off = (16 * g + n) * HH + 16 * kk + 4 * q;
            A0[g][kk] = ldw4(W_hh0 + off, K_TANH);
            AI[g][kk] = ldw4(W_ih1 + off, K_TANH);
        }
        #pragma unroll
        for (int g = 0; g < 4; ++g)
        #pragma unroll
        for (int r = 0; r < 4; ++r) {
            int j = 16 * g + 4 * q + r;
            e00[g][r] = K_TANH * (b_ih0[j] + b_hh0[j]);
            e10[g][r] = K_TANH * W_ih0[j];
        }
        #pragma unroll
        for (int kk = 0; kk < 4; ++kk)
            H0[kk] = ldw4(h_state + (size_t)(b0 + n) * HH + 16 * kk + 4 * q, 1.0f);
    } else {
        #pragma unroll
        for (int g = 0; g < 4; ++g)
        #pragma unroll
        for (int kk = 0; kk < 4; ++kk) {
            const int off = (16 * g + n) * HH + 16 * kk + 4 * q;
            AH[g][kk] = ldw4(W_hh1 + off, K_TANH);
        }
        #pragma unroll
        for (int g = 0; g < 4; ++g)
        #pragma unroll
        for (int r = 0; r < 4; ++r) {
            int j = 16 * g + 4 * q + r;
            e01[g][r] = K_TANH * (b_ih1[j] + b_hh1[j]);
            WO[g][r]  = W_out[j];
        }
        #pragma unroll
        for (int kk = 0; kk < 4; ++kk)
            H1[kk] = ldw4(h_state + (size_t)BB * HH + (size_t)(b0 + n) * HH
                                   + 16 * kk + 4 * q, 1.0f);
        bout = b_out[0];
    }

    // ---- stage x[b0..b0+15][0..139] into LDS [t][b] (128 threads) ----
    for (int i = tid; i < TT * BT; i += 128) {
        int t = i >> 4, b = i & 15;
        xs[t * 17 + b] = x[(size_t)(b0 + b) * TT + t];
    }
    __syncthreads();

    // ---- windowed loop: 36 iterations; A does window win, B does win-1 ----
    for (int win = 0; win <= TT / WIN; ++win) {
        if (wid == 0) {
            if (win < TT / WIN) {
                #pragma unroll
                for (int j = 0; j < WIN; ++j) {
                    const int p  = WIN * win + j;
                    const int pb = ((win & 1) ? WIN : 0) + j;   // p % (2*WIN)
                    float xt = xs[p * 17 + n];
                    // L0: d = Whh0.H0 + K*(bias0 + Wih0*x)
                    f32x4 d[4];
                    #pragma unroll
                    for (int g = 0; g < 4; ++g) {
                        f32x4 c;
                        #pragma unroll
                        for (int r = 0; r < 4; ++r) c[r] = e00[g][r] + e10[g][r] * xt;
                        #pragma unroll
                        for (int kk = 0; kk < 4; ++kk) c = MFMA16(A0[g][kk], H0[kk], c);
                        d[g] = c;
                    }
                    // tanh -> new H0 frags (D_g is next B-frag kk=g)
                    #pragma unroll
                    for (int g = 0; g < 4; ++g) {
                        half4 h;
                        #pragma unroll
                        for (int r = 0; r < 4; ++r) h[r] = (_Float16)tanh_ps(d[g][r]);
                        H0[g] = h;
                    }
                    // ih1 partial for wave B: ei = Wih1 . h0n
                    #pragma unroll
                    for (int g = 0; g < 4; ++g) {
                        f32x4 c = {0.f, 0.f, 0.f, 0.f};
                        #pragma unroll
                        for (int kk = 0; kk < 4; ++kk) c = MFMA16(AI[g][kk], H0[kk], c);
                        ei[pb][g][lane] = c;
                    }
                }
            }
        } else {
            if (win >= 1) {
                #pragma unroll
                for (int j = 0; j < WIN; ++j) {
                    const int s  = WIN * (win - 1) + j;
                    const int sb = (((win - 1) & 1) ? WIN : 0) + j;   // s % (2*WIN)
                    // L1: d = Whh1.H1 + K*bias1 + ei(s)
                    f32x4 d[4];
                    #pragma unroll
                    for (int g = 0; g < 4; ++g) {
                        f32x4 ep = ei[sb][g][lane];
                        f32x4 c;
                        #pragma unroll
                        for (int r = 0; r < 4; ++r) c[r] = e01[g][r] + ep[r];
                        #pragma unroll
                        for (int kk = 0; kk < 4; ++kk) c = MFMA16(AH[g][kk], H1[kk], c);
                        d[g] = c;
                    }
                    float pr = 0.f;
                    #pragma unroll
                    for (int g = 0; g < 4; ++g) {
                        half4 h;
                        #pragma unroll
                        for (int r = 0; r < 4; ++r) {
                            float hn = tanh_ps(d[g][r]);
                            pr += hn * WO[g][r];
                            h[r] = (_Float16)hn;
                        }
                        H1[g] = h;
                    }
                    pr += __shfl_xor(pr, 16, 64);
                    pr += __shfl_xor(pr, 32, 64);
                    if (lane < 16) pps[s * 17 + n] = pr + bout;
                }
            }
        }
        __syncthreads();   // lgkmcnt-only drain: no global ops in the loop
    }

    // ---- epilogue: flush y (both waves) ----
    for (int i = tid; i < TT * BT; i += 128) {
        int t = i >> 4, b = i & 15;
        out[(size_t)(b0 + b) * TT + t] = pps[t * 17 + b];
    }
    // ---- h_final: [2,B,H] appended after out[B*T] ----
    const size_t OFF = (size_t)BB * TT;
    if (wid == 0) {
        #pragma unroll
        for (int kk = 0; kk < 4; ++kk) {
            f32x4 v;
            #pragma unroll
            for (int i = 0; i < 4; ++i) v[i] = (float)H0[kk][i];
            *(f32x4*)(out + OFF + (size_t)(b0 + n) * HH + 16 * kk + 4 * q) = v;
        }
    } else {
        #pragma unroll
        for (int kk = 0; kk < 4; ++kk) {
            f32x4 v;
            #pragma unroll
            for (int i = 0; i < 4; ++i) v[i] = (float)H1[kk][i];
            *(f32x4*)(out + OFF + (size_t)BB * HH + (size_t)(b0 + n) * HH
                               + 16 * kk + 4 * q) = v;
        }
    }
}

extern "C" void kernel_launch(void* const* d_in, const int* in_sizes, int n_in,
                              void* d_out, int out_size, void* d_ws, size_t ws_size,
                              hipStream_t stream) {
    const float* x      = (const float*)d_in[0];
    const float* hst    = (const float*)d_in[1];
    const float* W_ih0  = (const float*)d_in[2];
    const float* W_hh0  = (const float*)d_in[3];
    const float* b_ih0  = (const float*)d_in[4];
    const float* b_hh0  = (const float*)d_in[5];
    const float* W_ih1  = (const float*)d_in[6];
    const float* W_hh1  = (const float*)d_in[7];
    const float* b_ih1  = (const float*)d_in[8];
    const float* b_hh1  = (const float*)d_in[9];
    const float* W_out  = (const float*)d_in[10];
    const float* b_outp = (const float*)d_in[11];
    float* out = (float*)d_out;

    dim3 grid(BB / BT);   // 512 blocks x 2 waves = 1024 waves = 1 per SIMD
    dim3 block(128);
    rnn_kernel<<<grid, block, 0, stream>>>(x, hst, W_ih0, W_hh0, b_ih0, b_hh0,
                                           W_ih1, W_hh1, b_ih1, b_hh1,
                                           W_out, b_outp, out);
}

// Round 15
// 151.823 us; speedup vs baseline: 1.1253x; 1.1253x over previous
//
#include <hip/hip_runtime.h>

#define TT 140
#define BB 8192
#define HH 64
#define BT 16   // batch tile per block (MFMA N)
#define FP ((TT - 1) & 1)   // parity of final step (=1)
#define K_TANH 2.88539008178f

typedef _Float16 half8 __attribute__((ext_vector_type(8)));
typedef _Float16 half4 __attribute__((ext_vector_type(4)));
typedef float    f32x4 __attribute__((ext_vector_type(4)));

#define MFMA16(a,b,c) __builtin_amdgcn_mfma_f32_16x16x32_f16(a, b, c, 0, 0, 0)

// tanh from PRE-SCALED argument (K_TANH folded into weights/biases):
// tanh(x) = 1 - 2/(2^(K*x)+1). Dependent chain: exp2 -> add -> rcp -> fma.
__device__ __forceinline__ float tanh_ps(float as) {
    float e = __builtin_amdgcn_exp2f(as);
    return 1.0f - 2.0f * __builtin_amdgcn_rcpf(e + 1.0f);
}

__device__ __forceinline__ half8 ld_frag(const _Float16* p) {
    return *(const half8*)__builtin_assume_aligned(p, 16);
}

// load 8 f32 weights, scale by K_TANH, convert to fp16
__device__ __forceinline__ half8 cvt_frag16s(const float* p) {
    f32x4 wa = *(const f32x4*)p;
    f32x4 wb = *(const f32x4*)(p + 4);
    half8 h;
    #pragma unroll
    for (int j = 0; j < 8; ++j)
        h[j] = (_Float16)(K_TANH * ((j < 4) ? wa[j] : wb[j - 4]));
    return h;
}

// r5-champion structure (84us: uniform 4-wave, fp16, K=32 MFMA, LDS h, 2
// blocks/CU) + three diagnosed fixes:
//  1. FRAGMENT-MAJOR h layout h[par][kt][q*16+n][8]: the old row-major HS=72
//     layout made every ds_read_b128 an 8-way bank conflict (banks 4*(col+q),
//     7.36M conflict cyc) sitting in the post-barrier critical chain. Reads
//     are now perfectly lane-linear (0-conflict); writes 2-way (free).
//  2. K_TANH prescaled into weights + bias/x folded into the MFMA C-init:
//     dependent chain is now MFMA -> exp2 directly (validated r10/r11).
//  3. s_setprio(1) around MFMA clusters (2 independent blocks/CU at
//     staggered phases -- the regime where setprio measured +4-7%).
// K16-MFMA reg-resident family (r11-r14) is dead: mfma_16x16x16_f16 measures
// ~16 cyc (4x the FLOP-rate tax vs 16x16x32's 4.85) -- derived from MfmaUtil.
__global__ __launch_bounds__(256, 2)
void rnn_kernel(const float* __restrict__ x,
                const float* __restrict__ h_state,
                const float* __restrict__ W_ih0,
                const float* __restrict__ W_hh0,
                const float* __restrict__ b_ih0,
                const float* __restrict__ b_hh0,
                const float* __restrict__ W_ih1,
                const float* __restrict__ W_hh1,
                const float* __restrict__ b_ih1,
                const float* __restrict__ b_hh1,
                const float* __restrict__ W_out,
                const float* __restrict__ b_out,
                float* __restrict__ out)
{
    // fragment-major: [parity][kt][fragslot = q*16 + batch][8 halfs] (4 KB ea)
    __shared__ __align__(16) _Float16 h0f[2][2][64][8];
    __shared__ __align__(16) _Float16 h1f[2][2][64][8];
    __shared__ float xs[TT * 17];        // x staged [t][b]
    __shared__ float pps[TT * 68];       // projection partials [t][w*17 + b]

    const int tid  = threadIdx.x;
    const int w    = tid >> 6;        // 0..3 = unit-quarter (both layers)
    const int lane = tid & 63;
    const int n    = lane & 15;       // MFMA col (batch)
    const int q    = lane >> 4;       // quad
    const int b0   = blockIdx.x * BT;

    // ---- A-fragments (fp16, K-prescaled): rows 16w+n of Whh0/Wih1/Whh1 ----
    half8 A0[2], AI[2], AH[2];
    #pragma unroll
    for (int kt = 0; kt < 2; ++kt) {
        const int off = (16 * w + n) * HH + 32 * kt + 8 * q;
        A0[kt] = cvt_frag16s(W_hh0 + off);
        AI[kt] = cvt_frag16s(W_ih1 + off);
        AH[kt] = cvt_frag16s(W_hh1 + off);
    }
    // epilogue scalars for this wave's quarter (units 16w+4q+r), K-prescaled
    float e00[4], e10[4], e01[4], WO[4];
    #pragma unroll
    for (int r = 0; r < 4; ++r) {
        int j = 16 * w + 4 * q + r;
        e00[r] = K_TANH * (b_ih0[j] + b_hh0[j]);
        e10[r] = K_TANH * W_ih0[j];
        e01[r] = K_TANH * (b_ih1[j] + b_hh1[j]);
        WO[r]  = W_out[j];
    }
    const float bout = b_out[0];

    // ---- stage x[b0..b0+15][0..139] into LDS [t][b] (256 threads) ----
    for (int i = tid; i < TT * BT; i += 256) {
        int t = i >> 4, b = i & 15;
        xs[t * 17 + b] = x[(size_t)(b0 + b) * TT + t];
    }
    // ---- init hidden state into parity-1 buffers (step "-1"), frag-major ----
    for (int i = tid; i < BT * HH; i += 256) {
        int b = i >> 6, u = i & 63;
        h0f[1][u >> 5][((u >> 3) & 3) * 16 + b][u & 7] =
            (_Float16)h_state[(size_t)(b0 + b) * HH + u];
        h1f[1][u >> 5][((u >> 3) & 3) * 16 + b][u & 7] =
            (_Float16)h_state[(size_t)BB * HH + (size_t)(b0 + b) * HH + u];
    }
    __syncthreads();

    // loop-invariant addressing
    const int rdslot = q * 16 + n;               // read slot (lane-linear)
    const int u0  = 16 * w + 4 * q;              // first unit this lane writes
    const int wkt = u0 >> 5, wqp = (u0 >> 3) & 3, woff = u0 & 7;

    // ---- pipelined phase loop: p=0..TT ----
    for (int p = 0; p <= TT; ++p) {
        const int rb = (p + 1) & 1;   // h0(p-1) read parity; h1(p-1) write par
        const int wb = p & 1;         // h0(p) write parity;  h1(p-2) read par
        half8 H0a = ld_frag(&h0f[rb][0][rdslot][0]);
        half8 H0b = ld_frag(&h0f[rb][1][rdslot][0]);
        half8 H1a = ld_frag(&h1f[wb][0][rdslot][0]);
        half8 H1b = ld_frag(&h1f[wb][1][rdslot][0]);
        float xt  = xs[p * 17 + n];

        if (p < TT) {
            // layer0 step p: bias+x folded into C-init; chain = MFMA -> exp2
            f32x4 c;
            #pragma unroll
            for (int r = 0; r < 4; ++r) c[r] = e00[r] + e10[r] * xt;
            __builtin_amdgcn_s_setprio(1);
            c = MFMA16(A0[0], H0a, c);
            c = MFMA16(A0[1], H0b, c);
            __builtin_amdgcn_s_setprio(0);
            half4 h4;
            #pragma unroll
            for (int r = 0; r < 4; ++r) h4[r] = (_Float16)tanh_ps(c[r]);
            *(half4*)(&h0f[wb][wkt][wqp * 16 + n][woff]) = h4;
        }
        if (p >= 1) {
            // layer1 step s=p-1: reuses H0a/b (= h0n(s)); two 2-deep chains
            f32x4 ci, ch = {0.f, 0.f, 0.f, 0.f};
            #pragma unroll
            for (int r = 0; r < 4; ++r) ci[r] = e01[r];
            __builtin_amdgcn_s_setprio(1);
            ci = MFMA16(AI[0], H0a, ci);
            ci = MFMA16(AI[1], H0b, ci);
            ch = MFMA16(AH[0], H1a, ch);
            ch = MFMA16(AH[1], H1b, ch);
            __builtin_amdgcn_s_setprio(0);
            f32x4 a = ci + ch;
            float pr = 0.f;
            half4 h4;
            #pragma unroll
            for (int r = 0; r < 4; ++r) {
                float hn = tanh_ps(a[r]);
                pr += hn * WO[r];
                h4[r] = (_Float16)hn;
            }
            *(half4*)(&h1f[rb][wkt][wqp * 16 + n][woff]) = h4;
            pr += __shfl_xor(pr, 16, 64);
            pr += __shfl_xor(pr, 32, 64);
            if (lane < 16) pps[(p - 1) * 68 + w * 17 + n] = pr;
        }
        __syncthreads();
    }

    // ---- epilogue: fold 4 quarter-partials + store y; wave w -> batches 4bq+w ----
    #pragma unroll
    for (int bq = 0; bq < 4; ++bq) {
        int b = 4 * bq + w;
        #pragma unroll
        for (int c = 0; c < 3; ++c) {
            int t = c * 64 + lane;
            if (t < TT)
                out[(size_t)(b0 + b) * TT + t] =
                    pps[t * 68 + b] + pps[t * 68 + 17 + b]
                  + pps[t * 68 + 34 + b] + pps[t * 68 + 51 + b] + bout;
        }
    }
    // ---- h_final: [2,B,H] appended after out[B*T]; final parity FP ----
    const size_t OFF = (size_t)BB * TT;
    for (int i = tid; i < BT * HH; i += 256) {
        int b = i >> 6, u = i & 63;
        out[OFF + (size_t)(b0 + b) * HH + u] =
            (float)h0f[FP][u >> 5][((u >> 3) & 3) * 16 + b][u & 7];
        out[OFF + (size_t)BB * HH + (size_t)(b0 + b) * HH + u] =
            (float)h1f[FP][u >> 5][((u >> 3) & 3) * 16 + b][u & 7];
    }
}

extern "C" void kernel_launch(void* const* d_in, const int* in_sizes, int n_in,
                              void* d_out, int out_size, void* d_ws, size_t ws_size,
                              hipStream_t stream) {
    const float* x      = (const float*)d_in[0];
    const float* hst    = (const float*)d_in[1];
    const float* W_ih0  = (const float*)d_in[2];
    const float* W_hh0  = (const float*)d_in[3];
    const float* b_ih0  = (const float*)d_in[4];
    const float* b_hh0  = (const float*)d_in[5];
    const float* W_ih1  = (const float*)d_in[6];
    const float* W_hh1  = (const float*)d_in[7];
    const float* b_ih1  = (const float*)d_in[8];
    const float* b_hh1  = (const float*)d_in[9];
    const float* W_out  = (const float*)d_in[10];
    const float* b_outp = (const float*)d_in[11];
    float* out = (float*)d_out;

    dim3 grid(BB / BT);   // 512 blocks x 4 waves = 2048 waves = 8/CU (2/SIMD)
    dim3 block(256);
    rnn_kernel<<<grid, block, 0, stream>>>(x, hst, W_ih0, W_hh0, b_ih0, b_hh0,
                                           W_ih1, W_hh1, b_ih1, b_hh1,
                                           W_out, b_outp, out);
}